// Round 7
// baseline (833.541 us; speedup 1.0000x reference)
//
#include <hip/hip_runtime.h>
#include <stdint.h>

#define NA 8400
#define MAXD 300
#define NMC 32
#define IMGD 640
#define MH 160
#define MW 160
#define PROTO_HW (MH*MW)        // 25600
#define IMG_HW (IMGD*IMGD)      // 409600

// ---- d_out layout (float elements) ----
#define OFF_RESULTS 0                         // 300*6
#define OFF_KEEP    1800                      // 300
#define OFF_MASKS   2100                      // 300*640*640
#define OFF_PIXELS  (2100 + 300*IMG_HW)       // 1
#define OFF_IMG     (OFF_PIXELS + 1)          // 3*640*640
#define OFF_CROP    (OFF_IMG + 3*IMG_HW)      // 4

// ---- ws layout (bytes) ----
#define WSO_MASKS160 0                                  // 300*25600*4
#define WSO_META     (MAXD*PROTO_HW*4)                  // ints: [0]=n_kept [1]=pix_count
#define WSO_BOXES    (WSO_META + 64)                    // 300*4 floats
#define WSO_MCOEF    (WSO_BOXES + MAXD*16)              // 300*32 floats
#define WSO_KEEPI    (WSO_MCOEF + MAXD*NMC*4)
#define WSO_KLIST    (WSO_KEEPI + MAXD*4)
#define WSO_EBOX     (WSO_KLIST + MAXD*4)               // 300*4 ints (xlo,xhi,ylo,yhi)

// ---------------- kernel 1: score + select + NMS, fully fused (1 block) ----------------
__global__ __launch_bounds__(1024)
void k_selnms(const float* __restrict__ pred, const float* __restrict__ conf_thres_p,
              const float* __restrict__ iou_thres_p,
              int* __restrict__ keepi, int* __restrict__ klist, int* __restrict__ meta,
              int* __restrict__ ebox, float* __restrict__ boxes_k,
              float* __restrict__ mcoef_k, float* __restrict__ out) {
    __shared__ unsigned cum[1024];
    __shared__ uint64_t kl[2048];
    __shared__ uint64_t srt[MAXD];
    __shared__ int s_cnt, s_bcut, s_nsel;
    __shared__ int sorder[MAXD];
    __shared__ int svf[MAXD];
    __shared__ float sscore[MAXD];
    __shared__ float bx[MAXD][4];
    __shared__ float sarea[MAXD];
    __shared__ uint64_t su[MAXD][5];
    __shared__ int skeep[MAXD];
    int t = threadIdx.x;
    float th = *conf_thres_p;

    // pass 1: histogram of confidences (1024 bins over [0,1))
    cum[t] = 0;
    __syncthreads();
    for (int i = t; i < NA; i += 1024) {
        float conf = pred[4 * NA + i];
        if (conf > th) {
            int bin = (int)(conf * 1024.0f);
            bin = bin < 0 ? 0 : (bin > 1023 ? 1023 : bin);
            atomicAdd(&cum[bin], 1u);
        }
    }
    __syncthreads();
    // suffix sum: cum[b] = #valid with bin >= b
    for (int off = 1; off < 1024; off <<= 1) {
        unsigned v = cum[t] + ((t + off < 1024) ? cum[t + off] : 0u);
        __syncthreads();
        cum[t] = v;
        __syncthreads();
    }
    if (t == 0) {
        s_cnt = 0;
        int tot = (int)cum[0];
        s_nsel = tot < MAXD ? tot : MAXD;
        s_bcut = 0;
    }
    __syncthreads();
    int nsel = s_nsel;
    if (nsel > 0) {
        if (cum[t] >= (unsigned)nsel && (t == 1023 || cum[t + 1] < (unsigned)nsel))
            s_bcut = t;   // unique: cum monotone non-increasing
    }
    __syncthreads();
    int bcut = s_bcut;
    // pass 2: collect candidates at/above cutoff bin
    if (nsel > 0) {
        for (int i = t; i < NA; i += 1024) {
            float conf = pred[4 * NA + i];
            if (conf > th) {
                int bin = (int)(conf * 1024.0f);
                bin = bin < 0 ? 0 : (bin > 1023 ? 1023 : bin);
                if (bin >= bcut) {
                    int p = atomicAdd(&s_cnt, 1);
                    if (p < 2048) {
                        unsigned fb = __float_as_uint(conf); // conf>0 -> order-preserving
                        kl[p] = ((uint64_t)fb << 32) | (unsigned)(NA - 1 - i);
                    }
                }
            }
        }
    }
    __syncthreads();
    int cnt = s_cnt < 2048 ? s_cnt : 2048;
    // rank-based top-300 (keys unique -> ranks form a permutation)
    for (int c = t; c < cnt; c += 1024) {
        uint64_t key = kl[c];
        int rank = 0;
        for (int j = 0; j < cnt; j++) rank += (kl[j] > key) ? 1 : 0;
        if (rank < MAXD) srt[rank] = key;
    }
    __syncthreads();
    // emit boxes / scores / order
    if (t < MAXD) {
        int v = (t < nsel) ? 1 : 0;
        uint64_t key = v ? srt[t] : 0;
        int idx = v ? (NA - 1 - (int)(key & 0xffffffffu)) : 0;
        sorder[t] = idx; svf[t] = v;
        sscore[t] = v ? __uint_as_float((unsigned)(key >> 32)) : -1.0f;
        float cx = pred[0 * NA + idx], cy = pred[1 * NA + idx];
        float w = pred[2 * NA + idx], h = pred[3 * NA + idx];
        float b0 = cx - w * 0.5f, b1 = cy - h * 0.5f, b2 = cx + w * 0.5f, b3 = cy + h * 0.5f;
        if (!v) { b0 = b1 = b2 = b3 = 0.f; }
        bx[t][0] = b0; bx[t][1] = b1; bx[t][2] = b2; bx[t][3] = b3;
        sarea[t] = (b2 - b0) * (b3 - b1);
        boxes_k[t * 4 + 0] = b0; boxes_k[t * 4 + 1] = b1;
        boxes_k[t * 4 + 2] = b2; boxes_k[t * 4 + 3] = b3;
    }
    __syncthreads();
    // mask coefficients for kept slots
    for (int m = t; m < MAXD * NMC; m += 1024) {
        int r = m >> 5, c = m & 31;
        mcoef_k[m] = svf[r] ? pred[(5 + c) * NA + sorder[r]] : 0.f;
    }
    // IOU bitmasks + expanded pixel boxes
    float ithr = *iou_thres_p;
    if (t < MAXD) {
        float x1 = bx[t][0], y1 = bx[t][1], x2 = bx[t][2], y2 = bx[t][3];
        float ar = sarea[t];
        uint64_t m[5] = {0, 0, 0, 0, 0};
        for (int j = 0; j < MAXD; j++) {
            float iw = fmaxf(fminf(x2, bx[j][2]) - fmaxf(x1, bx[j][0]), 0.f);
            float ih = fmaxf(fminf(y2, bx[j][3]) - fmaxf(y1, bx[j][1]), 0.f);
            float inter = iw * ih;
            float iou = inter / (ar + sarea[j] - inter + 1e-7f);
            if (iou > ithr) m[j >> 6] |= 1ull << (j & 63);
        }
        for (int w = 0; w < 5; w++) su[t][w] = m[w];
        // influence box: nonzero 160-cells p in [ceil(b*0.25), ceil(b2*0.25)-1];
        // cell p influences px in [4p-2, 4p+5]
        float db0 = x1 * 0.25f, db1 = y1 * 0.25f, db2 = x2 * 0.25f, db3 = y2 * 0.25f;
        int pxmin = max(0, (int)ceilf(db0));
        int pxmax = min(MW - 1, (int)ceilf(db2) - 1);
        int pymin = max(0, (int)ceilf(db1));
        int pymax = min(MH - 1, (int)ceilf(db3) - 1);
        int xlo = 1, xhi = 0, ylo = 1, yhi = 0;  // empty
        if (pxmin <= pxmax && pymin <= pymax) {
            xlo = max(0, 4 * pxmin - 2); xhi = min(IMGD - 1, 4 * pxmax + 5);
            ylo = max(0, 4 * pymin - 2); yhi = min(IMGD - 1, 4 * pymax + 5);
        }
        ebox[t * 4 + 0] = xlo; ebox[t * 4 + 1] = xhi;
        ebox[t * 4 + 2] = ylo; ebox[t * 4 + 3] = yhi;
    }
    __syncthreads();
    // sequential greedy NMS on wave 0
    if (t < 64) {
        uint64_t kwl = 0;
        int lane = t;
        for (int i = 0; i < MAXD; i++) {
            uint64_t x = (lane < 5) ? (su[i][lane] & kwl) : 0;
            bool sup = __any(x != 0);
            bool k = svf[i] && !sup;
            if (lane == (i >> 6) && k) kwl |= 1ull << (i & 63);
            if (lane == 0) { skeep[i] = k ? 1 : 0; keepi[i] = k ? 1 : 0; }
        }
    }
    __syncthreads();
    // results / keep outputs
    if (t < MAXD) {
        bool k = skeep[t] != 0;
        float bc0 = fminf(fmaxf(bx[t][0], 0.f), 640.f);
        float bc1 = fminf(fmaxf(bx[t][1], 0.f), 640.f);
        float bc2 = fminf(fmaxf(bx[t][2], 0.f), 640.f);
        float bc3 = fminf(fmaxf(bx[t][3], 0.f), 640.f);
        out[OFF_RESULTS + t * 6 + 0] = k ? bc0 : 0.f;
        out[OFF_RESULTS + t * 6 + 1] = k ? bc1 : 0.f;
        out[OFF_RESULTS + t * 6 + 2] = k ? bc2 : 0.f;
        out[OFF_RESULTS + t * 6 + 3] = k ? bc3 : 0.f;
        out[OFF_RESULTS + t * 6 + 4] = k ? sscore[t] : 0.f;
        out[OFF_RESULTS + t * 6 + 5] = 0.f;
        out[OFF_KEEP + t] = k ? 1.f : 0.f;
    }
    if (t == 0) {
        int n = 0;
        bool anyk = false;
        for (int i = 0; i < MAXD; i++)
            if (skeep[i]) { klist[n++] = i; anyk = true; }
        meta[0] = n;
        meta[1] = 0;   // pix_count accumulator for blend
        float amax = -INFINITY; int ai = 0;
        for (int i = 0; i < MAXD; i++) {
            float bc0 = fminf(fmaxf(bx[i][0], 0.f), 640.f);
            float bc1 = fminf(fmaxf(bx[i][1], 0.f), 640.f);
            float bc2 = fminf(fmaxf(bx[i][2], 0.f), 640.f);
            float bc3 = fminf(fmaxf(bx[i][3], 0.f), 640.f);
            float a = skeep[i] ? (bc2 - bc0) * (bc3 - bc1) : 0.f;
            if (a > amax) { amax = a; ai = i; }   // first max (jnp.argmax)
        }
        float mb0 = 0.f, mb1 = 0.f, mb2 = 0.f, mb3 = 0.f;
        if (anyk) {
            mb0 = fminf(fmaxf(bx[ai][0], 0.f), 640.f);
            mb1 = fminf(fmaxf(bx[ai][1], 0.f), 640.f);
            mb2 = fminf(fmaxf(bx[ai][2], 0.f), 640.f);
            mb3 = fminf(fmaxf(bx[ai][3], 0.f), 640.f);
        }
        int y1 = max((int)mb1 - 15, 0);
        int y2 = min((int)mb3 + 15, IMGD);
        int x1 = max((int)mb0 - 15, 0);
        int x2 = min((int)mb2 + 15, IMGD);
        out[OFF_CROP + 0] = (float)y1;
        out[OFF_CROP + 1] = (float)y2;
        out[OFF_CROP + 2] = (float)x1;
        out[OFF_CROP + 3] = (float)x2;
    }
}

// ---------------- kernel 2: 160x160 masks (kept dets only) ----------------
__global__ __launch_bounds__(256)
void k_masks(const float* __restrict__ proto, const float* __restrict__ mcoef_k,
             const float* __restrict__ boxes_k, const int* __restrict__ keepi,
             float* __restrict__ masks160) {
    int slot = blockIdx.y;
    if (!keepi[slot]) return;
    __shared__ float co[NMC];
    __shared__ float db[4];
    int t = threadIdx.x;
    if (t < NMC) co[t] = mcoef_k[slot * NMC + t];
    if (t >= NMC && t < NMC + 4) db[t - NMC] = boxes_k[slot * 4 + (t - NMC)] * 0.25f;
    __syncthreads();
    int p = blockIdx.x * 256 + t;
    float acc = 0.f;
#pragma unroll
    for (int k = 0; k < NMC; k++) acc = fmaf(co[k], proto[k * PROTO_HW + p], acc);
    float sig = 1.f / (1.f + expf(-acc));
    int py = p / MW, px = p - py * MW;
    float r = (float)px, c = (float)py;
    bool crop = (r >= db[0]) && (r < db[2]) && (c >= db[1]) && (c < db[3]);
    masks160[slot * PROTO_HW + p] = crop ? sig : 0.f;
}

// bilinear matching jax.image.resize 'linear' (160 -> 640, half-pixel centers, edge collapse)
__device__ __forceinline__ float bilin(const float* __restrict__ m, int y, int x) {
    float sy = 0.25f * (float)y - 0.375f;
    float sx = 0.25f * (float)x - 0.375f;
    int y0 = (int)floorf(sy); float fy = sy - (float)y0;
    int x0 = (int)floorf(sx); float fx = sx - (float)x0;
    if (y0 < 0) { y0 = 0; fy = 0.f; }
    int y1 = y0 + 1; if (y1 > MH - 1) { y1 = MH - 1; fy = 0.f; }
    if (x0 < 0) { x0 = 0; fx = 0.f; }
    int x1 = x0 + 1; if (x1 > MW - 1) { x1 = MW - 1; fx = 0.f; }
    const float* r0 = m + y0 * MW;
    const float* r1 = m + y1 * MW;
    float v00 = r0[x0], v01 = r0[x1], v10 = r1[x0], v11 = r1[x1];
    float t0 = fmaf(fy, v10, (1.f - fy) * v00);
    float t1 = fmaf(fy, v11, (1.f - fy) * v01);
    return fmaf(fx, t1, (1.f - fx) * t0);
}

// ---------------- kernel 3: masks_bin (zero or bilin, 16 px/thread) + fused blend slice ----------------
__global__ __launch_bounds__(256)
void k_upblend(const float* __restrict__ masks160, const int* __restrict__ keepi,
               const int* __restrict__ klist, const int* __restrict__ ebox,
               const int* __restrict__ meta, const float* __restrict__ img,
               float* __restrict__ out, int* __restrict__ pix_count) {
    int det = blockIdx.y;
    int t = threadIdx.x;
    int seg = (blockIdx.x * 256 + t) * 16;      // 16 | 640 -> never crosses a row
    int y = seg / IMGD, x16 = seg - y * IMGD;

    if (det < MAXD) {
        float4* dst = (float4*)(out + OFF_MASKS + (size_t)det * IMG_HW + seg);
        float4 z = {0.f, 0.f, 0.f, 0.f};
        bool inside = false;
        if (keepi[det]) {
            int xlo = ebox[det * 4 + 0], xhi = ebox[det * 4 + 1];
            int ylo = ebox[det * 4 + 2], yhi = ebox[det * 4 + 3];
            inside = (y >= ylo && y <= yhi && x16 + 15 >= xlo && x16 <= xhi);
        }
        if (!inside) {
            dst[0] = z; dst[1] = z; dst[2] = z; dst[3] = z;
            return;
        }
        const float* m = masks160 + (size_t)det * PROTO_HW;
        float v[16];
#pragma unroll
        for (int j = 0; j < 16; j++)
            v[j] = (bilin(m, y, x16 + j) > 0.5f) ? 1.f : 0.f;
#pragma unroll
        for (int q = 0; q < 4; q++) {
            float4 o = {v[4 * q], v[4 * q + 1], v[4 * q + 2], v[4 * q + 3]};
            dst[q] = o;
        }
        return;
    }

    // blend slice (det == MAXD)
    __shared__ int sxlo[MAXD], sxhi[MAXD], sylo[MAXD], syhi[MAXD], soff[MAXD];
    int n = meta[0];
    for (int i = t; i < n; i += 256) {
        int d = klist[i];
        sxlo[i] = ebox[d * 4 + 0]; sxhi[i] = ebox[d * 4 + 1];
        sylo[i] = ebox[d * 4 + 2]; syhi[i] = ebox[d * 4 + 3];
        soff[i] = d * PROTO_HW;
    }
    __syncthreads();
    float s[16];
#pragma unroll
    for (int j = 0; j < 16; j++) s[j] = 0.f;
    for (int i = 0; i < n; i++) {
        if (y >= sylo[i] && y <= syhi[i] && x16 + 15 >= sxlo[i] && x16 <= sxhi[i]) {
            const float* m = masks160 + soff[i];
#pragma unroll
            for (int j = 0; j < 16; j++)
                s[j] += (bilin(m, y, x16 + j) > 0.5f) ? 1.f : 0.f;
        }
    }
#pragma unroll
    for (int c = 0; c < 3; c++) {
        const float4* iv = (const float4*)(img + (size_t)c * IMG_HW + seg);
        float4* ov = (float4*)(out + OFF_IMG + (size_t)c * IMG_HW + seg);
        float bl = (c == 2) ? 1.f : 0.f;
#pragma unroll
        for (int q = 0; q < 4; q++) {
            float4 inq = iv[q];
            float4 o;
            float sv0 = s[4 * q], sv1 = s[4 * q + 1], sv2 = s[4 * q + 2], sv3 = s[4 * q + 3];
            o.x = (1.f - sv0) * inq.x + sv0 * (0.6f * inq.x + 0.4f * bl);
            o.y = (1.f - sv1) * inq.y + sv1 * (0.6f * inq.y + 0.4f * bl);
            o.z = (1.f - sv2) * inq.z + sv2 * (0.6f * inq.z + 0.4f * bl);
            o.w = (1.f - sv3) * inq.w + sv3 * (0.6f * inq.w + 0.4f * bl);
            ov[q] = o;
        }
    }
    int cnt = 0;
#pragma unroll
    for (int j = 0; j < 16; j++) cnt += (s[j] != 0.f) ? 1 : 0;
    for (int o2 = 32; o2 > 0; o2 >>= 1) cnt += __shfl_down(cnt, o2, 64);
    if ((t & 63) == 0) atomicAdd(pix_count, cnt);
}

__global__ void k_final(const int* __restrict__ meta, float* __restrict__ out) {
    out[OFF_PIXELS] = (float)meta[1];
}

extern "C" void kernel_launch(void* const* d_in, const int* in_sizes, int n_in,
                              void* d_out, int out_size, void* d_ws, size_t ws_size,
                              hipStream_t stream) {
    const float* pred       = (const float*)d_in[0];
    const float* proto      = (const float*)d_in[1];
    const float* img        = (const float*)d_in[2];
    const float* conf_thres = (const float*)d_in[3];
    const float* iou_thres  = (const float*)d_in[4];
    float* out = (float*)d_out;
    char* ws = (char*)d_ws;

    float* masks160 = (float*)(ws + WSO_MASKS160);
    int*   meta     = (int*)(ws + WSO_META);
    float* boxes_k  = (float*)(ws + WSO_BOXES);
    float* mcoef_k  = (float*)(ws + WSO_MCOEF);
    int*   keepi    = (int*)(ws + WSO_KEEPI);
    int*   klist    = (int*)(ws + WSO_KLIST);
    int*   ebox     = (int*)(ws + WSO_EBOX);

    k_selnms<<<dim3(1), dim3(1024), 0, stream>>>(pred, conf_thres, iou_thres,
                                                 keepi, klist, meta, ebox, boxes_k, mcoef_k, out);
    k_masks<<<dim3(PROTO_HW / 256, MAXD), dim3(256), 0, stream>>>(proto, mcoef_k, boxes_k, keepi, masks160);
    k_upblend<<<dim3(IMG_HW / 4096, MAXD + 1), dim3(256), 0, stream>>>(masks160, keepi, klist, ebox,
                                                                       meta, img, out, meta + 1);
    k_final<<<dim3(1), dim3(1), 0, stream>>>(meta, out);
}

// Round 11
// 747.996 us; speedup vs baseline: 1.1144x; 1.1144x over previous
//
#include <hip/hip_runtime.h>
#include <stdint.h>

#define NA 8400
#define MAXD 300
#define NMC 32
#define IMGD 640
#define MH 160
#define MW 160
#define PROTO_HW (MH*MW)        // 25600
#define IMG_HW (IMGD*IMGD)      // 409600

// ---- d_out layout (float elements) ----
#define OFF_RESULTS 0                         // 300*6
#define OFF_KEEP    1800                      // 300
#define OFF_MASKS   2100                      // 300*640*640
#define OFF_PIXELS  (2100 + 300*IMG_HW)       // 1
#define OFF_IMG     (OFF_PIXELS + 1)          // 3*640*640
#define OFF_CROP    (OFF_IMG + 3*IMG_HW)      // 4

// ---- ws layout (bytes) ----
#define WSO_MASKS160 0                                  // 300*25600*4
#define WSO_META     (MAXD*PROTO_HW*4)                  // ints: [0]=n_kept [1]=pix_count
#define WSO_BOXES    (WSO_META + 64)                    // 300*4 floats
#define WSO_MCOEF    (WSO_BOXES + MAXD*16)              // 300*32 floats
#define WSO_KEEPI    (WSO_MCOEF + MAXD*NMC*4)
#define WSO_KLIST    (WSO_KEEPI + MAXD*4)
#define WSO_EBOX     (WSO_KLIST + MAXD*4)               // 300*4 ints (xlo,xhi,ylo,yhi)

// ---------------- kernel 1: score + select + NMS, fully fused (1 block) ----------------
__global__ __launch_bounds__(1024)
void k_selnms(const float* __restrict__ pred, const float* __restrict__ conf_thres_p,
              const float* __restrict__ iou_thres_p,
              int* __restrict__ keepi, int* __restrict__ klist, int* __restrict__ meta,
              int* __restrict__ ebox, float* __restrict__ boxes_k,
              float* __restrict__ mcoef_k, float* __restrict__ out) {
    __shared__ unsigned cum[1024];
    __shared__ uint64_t kl[2048];
    __shared__ uint64_t srt[MAXD];
    __shared__ int s_cnt, s_bcut, s_nsel;
    __shared__ int sorder[MAXD];
    __shared__ int svf[MAXD];
    __shared__ float sscore[MAXD];
    __shared__ float bx[MAXD][4];
    __shared__ float sarea[MAXD];
    __shared__ uint64_t su[MAXD][5];
    __shared__ int skeep[MAXD];
    int t = threadIdx.x;
    float th = *conf_thres_p;

    // pass 1: histogram of confidences (1024 bins over [0,1))
    cum[t] = 0;
    __syncthreads();
    for (int i = t; i < NA; i += 1024) {
        float conf = pred[4 * NA + i];
        if (conf > th) {
            int bin = (int)(conf * 1024.0f);
            bin = bin < 0 ? 0 : (bin > 1023 ? 1023 : bin);
            atomicAdd(&cum[bin], 1u);
        }
    }
    __syncthreads();
    // suffix sum: cum[b] = #valid with bin >= b
    for (int off = 1; off < 1024; off <<= 1) {
        unsigned v = cum[t] + ((t + off < 1024) ? cum[t + off] : 0u);
        __syncthreads();
        cum[t] = v;
        __syncthreads();
    }
    if (t == 0) {
        s_cnt = 0;
        int tot = (int)cum[0];
        s_nsel = tot < MAXD ? tot : MAXD;
        s_bcut = 0;
    }
    __syncthreads();
    int nsel = s_nsel;
    if (nsel > 0) {
        if (cum[t] >= (unsigned)nsel && (t == 1023 || cum[t + 1] < (unsigned)nsel))
            s_bcut = t;   // unique: cum monotone non-increasing
    }
    __syncthreads();
    int bcut = s_bcut;
    // pass 2: collect candidates at/above cutoff bin
    if (nsel > 0) {
        for (int i = t; i < NA; i += 1024) {
            float conf = pred[4 * NA + i];
            if (conf > th) {
                int bin = (int)(conf * 1024.0f);
                bin = bin < 0 ? 0 : (bin > 1023 ? 1023 : bin);
                if (bin >= bcut) {
                    int p = atomicAdd(&s_cnt, 1);
                    if (p < 2048) {
                        unsigned fb = __float_as_uint(conf); // conf>0 -> order-preserving
                        kl[p] = ((uint64_t)fb << 32) | (unsigned)(NA - 1 - i);
                    }
                }
            }
        }
    }
    __syncthreads();
    int cnt = s_cnt < 2048 ? s_cnt : 2048;
    // rank-based top-300 (keys unique -> ranks form a permutation)
    for (int c = t; c < cnt; c += 1024) {
        uint64_t key = kl[c];
        int rank = 0;
        for (int j = 0; j < cnt; j++) rank += (kl[j] > key) ? 1 : 0;
        if (rank < MAXD) srt[rank] = key;
    }
    __syncthreads();
    // emit boxes / scores / order
    if (t < MAXD) {
        int v = (t < nsel) ? 1 : 0;
        uint64_t key = v ? srt[t] : 0;
        int idx = v ? (NA - 1 - (int)(key & 0xffffffffu)) : 0;
        sorder[t] = idx; svf[t] = v;
        sscore[t] = v ? __uint_as_float((unsigned)(key >> 32)) : -1.0f;
        float cx = pred[0 * NA + idx], cy = pred[1 * NA + idx];
        float w = pred[2 * NA + idx], h = pred[3 * NA + idx];
        float b0 = cx - w * 0.5f, b1 = cy - h * 0.5f, b2 = cx + w * 0.5f, b3 = cy + h * 0.5f;
        if (!v) { b0 = b1 = b2 = b3 = 0.f; }
        bx[t][0] = b0; bx[t][1] = b1; bx[t][2] = b2; bx[t][3] = b3;
        sarea[t] = (b2 - b0) * (b3 - b1);
        boxes_k[t * 4 + 0] = b0; boxes_k[t * 4 + 1] = b1;
        boxes_k[t * 4 + 2] = b2; boxes_k[t * 4 + 3] = b3;
    }
    __syncthreads();
    // mask coefficients for kept slots
    for (int m = t; m < MAXD * NMC; m += 1024) {
        int r = m >> 5, c = m & 31;
        mcoef_k[m] = svf[r] ? pred[(5 + c) * NA + sorder[r]] : 0.f;
    }
    // IOU bitmasks + expanded pixel boxes
    float ithr = *iou_thres_p;
    if (t < MAXD) {
        float x1 = bx[t][0], y1 = bx[t][1], x2 = bx[t][2], y2 = bx[t][3];
        float ar = sarea[t];
        uint64_t m[5] = {0, 0, 0, 0, 0};
        for (int j = 0; j < MAXD; j++) {
            float iw = fmaxf(fminf(x2, bx[j][2]) - fmaxf(x1, bx[j][0]), 0.f);
            float ih = fmaxf(fminf(y2, bx[j][3]) - fmaxf(y1, bx[j][1]), 0.f);
            float inter = iw * ih;
            float iou = inter / (ar + sarea[j] - inter + 1e-7f);
            if (iou > ithr) m[j >> 6] |= 1ull << (j & 63);
        }
        for (int w = 0; w < 5; w++) su[t][w] = m[w];
        // influence box: nonzero 160-cells p in [ceil(b*0.25), ceil(b2*0.25)-1];
        // cell p influences px in [4p-2, 4p+5]
        float db0 = x1 * 0.25f, db1 = y1 * 0.25f, db2 = x2 * 0.25f, db3 = y2 * 0.25f;
        int pxmin = max(0, (int)ceilf(db0));
        int pxmax = min(MW - 1, (int)ceilf(db2) - 1);
        int pymin = max(0, (int)ceilf(db1));
        int pymax = min(MH - 1, (int)ceilf(db3) - 1);
        int xlo = 1, xhi = 0, ylo = 1, yhi = 0;  // empty
        if (pxmin <= pxmax && pymin <= pymax) {
            xlo = max(0, 4 * pxmin - 2); xhi = min(IMGD - 1, 4 * pxmax + 5);
            ylo = max(0, 4 * pymin - 2); yhi = min(IMGD - 1, 4 * pymax + 5);
        }
        ebox[t * 4 + 0] = xlo; ebox[t * 4 + 1] = xhi;
        ebox[t * 4 + 2] = ylo; ebox[t * 4 + 3] = yhi;
    }
    __syncthreads();
    // sequential greedy NMS on wave 0
    if (t < 64) {
        uint64_t kwl = 0;
        int lane = t;
        for (int i = 0; i < MAXD; i++) {
            uint64_t x = (lane < 5) ? (su[i][lane] & kwl) : 0;
            bool sup = __any(x != 0);
            bool k = svf[i] && !sup;
            if (lane == (i >> 6) && k) kwl |= 1ull << (i & 63);
            if (lane == 0) { skeep[i] = k ? 1 : 0; keepi[i] = k ? 1 : 0; }
        }
    }
    __syncthreads();
    // results / keep outputs
    if (t < MAXD) {
        bool k = skeep[t] != 0;
        float bc0 = fminf(fmaxf(bx[t][0], 0.f), 640.f);
        float bc1 = fminf(fmaxf(bx[t][1], 0.f), 640.f);
        float bc2 = fminf(fmaxf(bx[t][2], 0.f), 640.f);
        float bc3 = fminf(fmaxf(bx[t][3], 0.f), 640.f);
        out[OFF_RESULTS + t * 6 + 0] = k ? bc0 : 0.f;
        out[OFF_RESULTS + t * 6 + 1] = k ? bc1 : 0.f;
        out[OFF_RESULTS + t * 6 + 2] = k ? bc2 : 0.f;
        out[OFF_RESULTS + t * 6 + 3] = k ? bc3 : 0.f;
        out[OFF_RESULTS + t * 6 + 4] = k ? sscore[t] : 0.f;
        out[OFF_RESULTS + t * 6 + 5] = 0.f;
        out[OFF_KEEP + t] = k ? 1.f : 0.f;
    }
    if (t == 0) {
        int n = 0;
        bool anyk = false;
        for (int i = 0; i < MAXD; i++)
            if (skeep[i]) { klist[n++] = i; anyk = true; }
        meta[0] = n;
        meta[1] = 0;   // pix_count accumulator for blend
        float amax = -INFINITY; int ai = 0;
        for (int i = 0; i < MAXD; i++) {
            float bc0 = fminf(fmaxf(bx[i][0], 0.f), 640.f);
            float bc1 = fminf(fmaxf(bx[i][1], 0.f), 640.f);
            float bc2 = fminf(fmaxf(bx[i][2], 0.f), 640.f);
            float bc3 = fminf(fmaxf(bx[i][3], 0.f), 640.f);
            float a = skeep[i] ? (bc2 - bc0) * (bc3 - bc1) : 0.f;
            if (a > amax) { amax = a; ai = i; }   // first max (jnp.argmax)
        }
        float mb0 = 0.f, mb1 = 0.f, mb2 = 0.f, mb3 = 0.f;
        if (anyk) {
            mb0 = fminf(fmaxf(bx[ai][0], 0.f), 640.f);
            mb1 = fminf(fmaxf(bx[ai][1], 0.f), 640.f);
            mb2 = fminf(fmaxf(bx[ai][2], 0.f), 640.f);
            mb3 = fminf(fmaxf(bx[ai][3], 0.f), 640.f);
        }
        int y1 = max((int)mb1 - 15, 0);
        int y2 = min((int)mb3 + 15, IMGD);
        int x1 = max((int)mb0 - 15, 0);
        int x2 = min((int)mb2 + 15, IMGD);
        out[OFF_CROP + 0] = (float)y1;
        out[OFF_CROP + 1] = (float)y2;
        out[OFF_CROP + 2] = (float)x1;
        out[OFF_CROP + 3] = (float)x2;
    }
}

// ---------------- kernel 2: 160x160 masks (kept dets only) ----------------
__global__ __launch_bounds__(256)
void k_masks(const float* __restrict__ proto, const float* __restrict__ mcoef_k,
             const float* __restrict__ boxes_k, const int* __restrict__ keepi,
             float* __restrict__ masks160) {
    int slot = blockIdx.y;
    if (!keepi[slot]) return;
    __shared__ float co[NMC];
    __shared__ float db[4];
    int t = threadIdx.x;
    if (t < NMC) co[t] = mcoef_k[slot * NMC + t];
    if (t >= NMC && t < NMC + 4) db[t - NMC] = boxes_k[slot * 4 + (t - NMC)] * 0.25f;
    __syncthreads();
    int p = blockIdx.x * 256 + t;
    float acc = 0.f;
#pragma unroll
    for (int k = 0; k < NMC; k++) acc = fmaf(co[k], proto[k * PROTO_HW + p], acc);
    float sig = 1.f / (1.f + expf(-acc));
    int py = p / MW, px = p - py * MW;
    float r = (float)px, c = (float)py;
    bool crop = (r >= db[0]) && (r < db[2]) && (c >= db[1]) && (c < db[3]);
    masks160[slot * PROTO_HW + p] = crop ? sig : 0.f;
}

// bilinear matching jax.image.resize 'linear' (160 -> 640, half-pixel centers, edge collapse)
__device__ __forceinline__ float bilin(const float* __restrict__ m, int y, int x) {
    float sy = 0.25f * (float)y - 0.375f;
    float sx = 0.25f * (float)x - 0.375f;
    int y0 = (int)floorf(sy); float fy = sy - (float)y0;
    int x0 = (int)floorf(sx); float fx = sx - (float)x0;
    if (y0 < 0) { y0 = 0; fy = 0.f; }
    int y1 = y0 + 1; if (y1 > MH - 1) { y1 = MH - 1; fy = 0.f; }
    if (x0 < 0) { x0 = 0; fx = 0.f; }
    int x1 = x0 + 1; if (x1 > MW - 1) { x1 = MW - 1; fx = 0.f; }
    const float* r0 = m + y0 * MW;
    const float* r1 = m + y1 * MW;
    float v00 = r0[x0], v01 = r0[x1], v10 = r1[x0], v11 = r1[x1];
    float t0 = fmaf(fy, v10, (1.f - fy) * v00);
    float t1 = fmaf(fy, v11, (1.f - fy) * v01);
    return fmaf(fx, t1, (1.f - fx) * t0);
}

// ---------------- kernel 3: masks_bin (4 px/thread, lane-contiguous) + fused blend slice ----------------
__global__ __launch_bounds__(256)
void k_upblend(const float* __restrict__ masks160, const int* __restrict__ keepi,
               const int* __restrict__ klist, const int* __restrict__ ebox,
               const int* __restrict__ meta, const float* __restrict__ img,
               float* __restrict__ out, int* __restrict__ pix_count) {
    int det = blockIdx.y;
    int t = threadIdx.x;
    int base = (blockIdx.x * 256 + t) * 4;      // 4 | 640 -> never crosses a row; wave = 1KB contiguous
    int y = base / IMGD, x = base - y * IMGD;

    if (det < MAXD) {
        float4 o = {0.f, 0.f, 0.f, 0.f};
        if (keepi[det]) {
            int xlo = ebox[det * 4 + 0], xhi = ebox[det * 4 + 1];
            int ylo = ebox[det * 4 + 2], yhi = ebox[det * 4 + 3];
            if (y >= ylo && y <= yhi && x + 3 >= xlo && x <= xhi) {
                const float* m = masks160 + (size_t)det * PROTO_HW;
                o.x = (bilin(m, y, x)     > 0.5f) ? 1.f : 0.f;
                o.y = (bilin(m, y, x + 1) > 0.5f) ? 1.f : 0.f;
                o.z = (bilin(m, y, x + 2) > 0.5f) ? 1.f : 0.f;
                o.w = (bilin(m, y, x + 3) > 0.5f) ? 1.f : 0.f;
            }
        }
        *(float4*)(out + OFF_MASKS + (size_t)det * IMG_HW + base) = o;
        return;
    }

    // blend slice (det == MAXD)
    __shared__ int sxlo[MAXD], sxhi[MAXD], sylo[MAXD], syhi[MAXD], soff[MAXD];
    int n = meta[0];
    for (int i = t; i < n; i += 256) {
        int d = klist[i];
        sxlo[i] = ebox[d * 4 + 0]; sxhi[i] = ebox[d * 4 + 1];
        sylo[i] = ebox[d * 4 + 2]; syhi[i] = ebox[d * 4 + 3];
        soff[i] = d * PROTO_HW;
    }
    __syncthreads();
    float4 s = {0.f, 0.f, 0.f, 0.f};
    for (int i = 0; i < n; i++) {
        if (y >= sylo[i] && y <= syhi[i] && x + 3 >= sxlo[i] && x <= sxhi[i]) {
            const float* m = masks160 + soff[i];
            s.x += (bilin(m, y, x)     > 0.5f) ? 1.f : 0.f;
            s.y += (bilin(m, y, x + 1) > 0.5f) ? 1.f : 0.f;
            s.z += (bilin(m, y, x + 2) > 0.5f) ? 1.f : 0.f;
            s.w += (bilin(m, y, x + 3) > 0.5f) ? 1.f : 0.f;
        }
    }
#pragma unroll
    for (int c = 0; c < 3; c++) {
        float4 iv = *(const float4*)(img + (size_t)c * IMG_HW + base);
        float bl = (c == 2) ? 1.f : 0.f;
        float4 ov;
        ov.x = (1.f - s.x) * iv.x + s.x * (0.6f * iv.x + 0.4f * bl);
        ov.y = (1.f - s.y) * iv.y + s.y * (0.6f * iv.y + 0.4f * bl);
        ov.z = (1.f - s.z) * iv.z + s.z * (0.6f * iv.z + 0.4f * bl);
        ov.w = (1.f - s.w) * iv.w + s.w * (0.6f * iv.w + 0.4f * bl);
        *(float4*)(out + OFF_IMG + (size_t)c * IMG_HW + base) = ov;
    }
    int cnt = (s.x != 0.f) + (s.y != 0.f) + (s.z != 0.f) + (s.w != 0.f);
    for (int o2 = 32; o2 > 0; o2 >>= 1) cnt += __shfl_down(cnt, o2, 64);
    if ((t & 63) == 0) atomicAdd(pix_count, cnt);
}

__global__ void k_final(const int* __restrict__ meta, float* __restrict__ out) {
    out[OFF_PIXELS] = (float)meta[1];
}

extern "C" void kernel_launch(void* const* d_in, const int* in_sizes, int n_in,
                              void* d_out, int out_size, void* d_ws, size_t ws_size,
                              hipStream_t stream) {
    const float* pred       = (const float*)d_in[0];
    const float* proto      = (const float*)d_in[1];
    const float* img        = (const float*)d_in[2];
    const float* conf_thres = (const float*)d_in[3];
    const float* iou_thres  = (const float*)d_in[4];
    float* out = (float*)d_out;
    char* ws = (char*)d_ws;

    float* masks160 = (float*)(ws + WSO_MASKS160);
    int*   meta     = (int*)(ws + WSO_META);
    float* boxes_k  = (float*)(ws + WSO_BOXES);
    float* mcoef_k  = (float*)(ws + WSO_MCOEF);
    int*   keepi    = (int*)(ws + WSO_KEEPI);
    int*   klist    = (int*)(ws + WSO_KLIST);
    int*   ebox     = (int*)(ws + WSO_EBOX);

    k_selnms<<<dim3(1), dim3(1024), 0, stream>>>(pred, conf_thres, iou_thres,
                                                 keepi, klist, meta, ebox, boxes_k, mcoef_k, out);
    k_masks<<<dim3(PROTO_HW / 256, MAXD), dim3(256), 0, stream>>>(proto, mcoef_k, boxes_k, keepi, masks160);
    k_upblend<<<dim3(IMG_HW / 1024, MAXD + 1), dim3(256), 0, stream>>>(masks160, keepi, klist, ebox,
                                                                       meta, img, out, meta + 1);
    k_final<<<dim3(1), dim3(1), 0, stream>>>(meta, out);
}